// Round 3
// baseline (209.128 us; speedup 1.0000x reference)
//
#include <hip/hip_runtime.h>
#include <math.h>

// Problem constants (fixed by setup_inputs)
#define BB 512
#define TT 64
#define SS 128
#define OO 32
#define DTC 0.05f

// -DT / sqrt(S) = -0.05 / 11.313708498984761
#define NEG_DT_INVSQ (-0.004419417382415922f)
#define HALF_LOG2PI 0.9189385332046727f

typedef float f4 __attribute__((ext_vector_type(4)));

// W layout: logical (r,c) lives at Wf[r*128 + (c ^ SW(r))].
// SW(r) = 4*((r>>3)&7): XOR of col bits [4:2] by row-tile id. Any 4-multiple
// row stride has (8*ti*stride) % 32 == 0, so only a swizzle (not padding)
// spreads the 8 rows of a thread-tile across banks. Verified conflict-free
// per 8-lane octet for: build writes, panel loads, sweep r/w, phase-2 reads.
#define SW(r) ((((r) >> 3) & 7) << 2)

__device__ __forceinline__ f4 ld4(const float* a) { return *reinterpret_cast<const f4*>(a); }
__device__ __forceinline__ void st4(float* a, f4 v) { *reinterpret_cast<f4*>(a) = v; }

// One block per batch b. Phases:
//  0: unscale p -> r (softplus), x0 (sigmoid); build W = K^T (swizzled LDS)
//  1: blocked Gauss-Jordan inversion, NB=8, doctored rank-8 updates:
//     Cd = colpanel - E, Rw = rowpanel + E^T, T = Pinv*Rw, W -= Cd*T
//     (reproduces all four GJ block cases; no pivoting, K diag-dominant)
//     -> W = (K^T)^-1 = M^T
//  2: thread keeps its 8x8 tile of M^T in registers; 64 steps of
//     x <- M x via register FMA + 16-way LDS partial reduce; project
//     y = C x + d; accumulate Gaussian NLL
__global__ __launch_bounds__(256, 2) void fused_kernel(
    const float* __restrict__ p, const float* __restrict__ A,
    const float* __restrict__ C, const float* __restrict__ d,
    const float* __restrict__ sigma_p, const float* __restrict__ my,
    const int* __restrict__ pscale, float* __restrict__ ws_partial)
{
    __shared__ __align__(16) float Wf[SS * SS];     // 64 KiB, swizzled
    __shared__ __align__(16) float PsT[8 * 12];     // PsT[j][i] = Pinv[i][j]
    __shared__ __align__(16) float xv[SS];
    __shared__ __align__(16) float ptile[16 * 132]; // phase-2 partials; phase-0 r
    __shared__ float redsm[4];

    const int tid = threadIdx.x;
    const int b = blockIdx.x;

    // ---------------- phase 0: setup ----------------
    if (tid < SS) {
        float pv = p[b * SS + tid];
        int sc = pscale[tid];
        // amici unscale: 0=none, 1=ln, 2=log10
        float ps = (sc == 0) ? pv : ((sc == 1) ? expf(pv) : exp10f(pv));
        // softplus (stable form) -> r, stored in ptile scratch
        ptile[tid] = fmaxf(ps, 0.0f) + log1pf(expf(-fabsf(ps)));
        xv[tid] = 1.0f / (1.0f + expf(-ps));          // sigmoid -> x0
    }
    __syncthreads();

    // W[i][j] = K[j][i] = -DT*As[j][i] + (i==j)*(1 + DT*r_i); A[m]=As-row j, col i
    #pragma unroll 8
    for (int it = 0; it < (SS * SS) / 256; ++it) {
        int m = it * 256 + tid;
        int i = m & (SS - 1);
        int j = m >> 7;
        float v = NEG_DT_INVSQ * A[m];
        if (i == j) v += fmaf(DTC, ptile[i], 1.0f);
        Wf[i * SS + (j ^ SW(i))] = v;
    }
    __syncthreads();

    // ---------------- phase 1: blocked Gauss-Jordan, NB = 8 ----------------
    const int ti = tid & 15;          // row-tile: rows 8*ti .. 8*ti+7
    const int tj = tid >> 4;          // col-tile: cols 8*tj .. 8*tj+7
    const int swt = (ti & 7) << 2;    // swizzle for this thread's rows
    const int pcA = (8 * tj) ^ swt;   // phys col of logical 8tj..+3 (own rows)
    const int pcB = (8 * tj + 4) ^ swt;

    for (int kb = 0; kb < 16; ++kb) {
        const int k0 = kb * 8;
        const int swk = (kb & 7) << 2;   // swizzle of pivot-panel rows k0..k0+7

        // Cd: doctored col-panel (pre-update W), own rows, logical cols k0..k0+7
        f4 cda[8], cdb[8];
        {
            const int qA = k0 ^ swt, qB = (k0 + 4) ^ swt;
            #pragma unroll
            for (int rr = 0; rr < 8; ++rr) {
                int base = (8 * ti + rr) * SS;
                cda[rr] = ld4(&Wf[base + qA]);
                cdb[rr] = ld4(&Wf[base + qB]);
            }
            if (ti == kb) {   // subtract identity at block rows
                #pragma unroll
                for (int rr = 0; rr < 8; ++rr) {
                    if (rr < 4) cda[rr][rr] -= 1.0f;
                    else        cdb[rr][rr - 4] -= 1.0f;
                }
            }
        }

        // wave 0: 8x8 pivot inverse via shfl-only doctored rank-1 GJ
        if (tid < 64) {
            int gi = tid >> 3, gj = tid & 7;
            float q = Wf[(k0 + gi) * SS + ((k0 + gj) ^ swk)];
            #pragma unroll
            for (int kk = 0; kk < 8; ++kk) {
                float ck = __shfl(q, (gi << 3) | kk, 64);   // P[gi][kk]
                float pr = __shfl(q, (kk << 3) | gj, 64);   // P[kk][gj]
                float pv = __shfl(q, (kk << 3) | kk, 64);   // P[kk][kk]
                float ip = 1.0f / pv;
                float ckd = ck - ((gi == kk) ? 1.0f : 0.0f);
                float prd = pr + ((gj == kk) ? 1.0f : 0.0f);
                q = fmaf(-ckd, prd * ip, q);
            }
            PsT[gj * 12 + gi] = q;   // PsT[j][i] = Pinv[i][j]
        }
        __syncthreads();   // PsT ready; W still unmodified

        // T-slice: T[i][own 8 cols] = sum_j Pinv[i][j] * (W[k0+j][c] + E)
        f4 ta[8] = {f4{0,0,0,0},f4{0,0,0,0},f4{0,0,0,0},f4{0,0,0,0},
                    f4{0,0,0,0},f4{0,0,0,0},f4{0,0,0,0},f4{0,0,0,0}};
        f4 tb[8] = {f4{0,0,0,0},f4{0,0,0,0},f4{0,0,0,0},f4{0,0,0,0},
                    f4{0,0,0,0},f4{0,0,0,0},f4{0,0,0,0},f4{0,0,0,0}};
        {
            const int rc0 = (8 * tj) ^ swk, rc1 = (8 * tj + 4) ^ swk;
            #pragma unroll
            for (int j = 0; j < 8; ++j) {
                int base = (k0 + j) * SS;
                f4 rwa = ld4(&Wf[base + rc0]);
                f4 rwb = ld4(&Wf[base + rc1]);
                if (tj == kb) {   // add identity at block cols (c == k0+j)
                    if (j < 4) rwa[j] += 1.0f;
                    else       rwb[j - 4] += 1.0f;
                }
                f4 pa = ld4(&PsT[j * 12]);       // Pinv[0..3][j]
                f4 pb = ld4(&PsT[j * 12 + 4]);   // Pinv[4..7][j]
                #pragma unroll
                for (int i = 0; i < 4; ++i) {
                    ta[i] += pa[i] * rwa;  tb[i] += pa[i] * rwb;
                    ta[i + 4] += pb[i] * rwa;  tb[i + 4] += pb[i] * rwb;
                }
            }
        }
        __syncthreads();   // all row-panel reads done before sweep writes

        // sweep: W[own tile] -= Cd * T   (disjoint tiles: no races)
        #pragma unroll
        for (int rr = 0; rr < 8; ++rr) {
            int base = (8 * ti + rr) * SS;
            f4 va = ld4(&Wf[base + pcA]);
            f4 vb = ld4(&Wf[base + pcB]);
            #pragma unroll
            for (int i = 0; i < 8; ++i) {
                float cdi = (i < 4) ? cda[rr][i] : cdb[rr][i - 4];
                va -= cdi * ta[i];
                vb -= cdi * tb[i];
            }
            st4(&Wf[base + pcA], va);
            st4(&Wf[base + pcB], vb);
        }
        __syncthreads();   // step complete; W stable for next extraction
    }
    // W now holds M^T (M = K^-1)

    // ---------------- phase 2: register-tile iteration + NLL ----------------
    f4 wta[8], wtb[8];   // own 8x8 tile of M^T: rows 8ti+rr, cols 8tj..+7
    #pragma unroll
    for (int rr = 0; rr < 8; ++rr) {
        int base = (8 * ti + rr) * SS;
        wta[rr] = ld4(&Wf[base + pcA]);
        wtb[rr] = ld4(&Wf[base + pcB]);
    }

    const int o = tid >> 3, cc = tid & 7;
    float Creg[16];
    #pragma unroll
    for (int i2 = 0; i2 < 16; ++i2) Creg[i2] = C[o * SS + i2 * 8 + cc];
    const float dval = d[o];
    const float sgp = sigma_p[o];
    const float isig = expf(-sgp);             // 1 / sigmay
    const float cterm = sgp + HALF_LOG2PI;     // log(sigmay) + 0.5*log(2pi)
    float lacc = 0.0f;
    const float* __restrict__ myb = my + (size_t)b * (TT * OO);

    for (int t = 0; t < TT; ++t) {
        // partial x_new[8tj+q] over rows 8ti..+7, all in registers
        f4 xa = ld4(&xv[8 * ti]);
        f4 xb = ld4(&xv[8 * ti + 4]);
        f4 pa = {0, 0, 0, 0}, pb = {0, 0, 0, 0};
        #pragma unroll
        for (int rr = 0; rr < 8; ++rr) {
            float xr = (rr < 4) ? xa[rr] : xb[rr - 4];
            pa += xr * wta[rr];
            pb += xr * wtb[rr];
        }
        st4(&ptile[ti * 132 + 8 * tj], pa);
        st4(&ptile[ti * 132 + 8 * tj + 4], pb);
        __syncthreads();
        if (tid < SS) {
            float s = 0.0f;
            #pragma unroll
            for (int g = 0; g < 16; ++g) s += ptile[g * 132 + tid];
            xv[tid] = s;
        }
        __syncthreads();

        // y_o = C[o,:] . x  (8-lane split, s = i2*8+cc: conflict-free xv reads)
        float py = 0.0f;
        #pragma unroll
        for (int i2 = 0; i2 < 16; ++i2)
            py = fmaf(Creg[i2], xv[i2 * 8 + cc], py);
        py += __shfl_xor(py, 1);
        py += __shfl_xor(py, 2);
        py += __shfl_xor(py, 4);
        if (cc == 0) {
            float e = (py + dval - myb[t * OO + o]) * isig;
            lacc += fmaf(0.5f * e, e, cterm);
        }
    }

    // block-sum lacc
    #pragma unroll
    for (int off = 32; off >= 1; off >>= 1) lacc += __shfl_xor(lacc, off);
    if ((tid & 63) == 0) redsm[tid >> 6] = lacc;
    __syncthreads();
    if (tid == 0)
        ws_partial[b] = redsm[0] + redsm[1] + redsm[2] + redsm[3];
}

__global__ void reduce_kernel(const float* __restrict__ ws_partial,
                              float* __restrict__ out)
{
    __shared__ double sm[8];
    int tid = threadIdx.x;   // 512 threads
    double v = (double)ws_partial[tid];
    #pragma unroll
    for (int off = 32; off >= 1; off >>= 1) v += __shfl_xor(v, off);
    if ((tid & 63) == 0) sm[tid >> 6] = v;
    __syncthreads();
    if (tid == 0) {
        double s = 0.0;
        for (int i = 0; i < 8; ++i) s += sm[i];
        out[0] = (float)(-s);   // llh = -sum(Jy)
    }
}

extern "C" void kernel_launch(void* const* d_in, const int* in_sizes, int n_in,
                              void* d_out, int out_size, void* d_ws, size_t ws_size,
                              hipStream_t stream) {
    const float* p       = (const float*)d_in[0];
    const float* A       = (const float*)d_in[1];
    const float* C       = (const float*)d_in[2];
    const float* d       = (const float*)d_in[3];
    const float* sigma_p = (const float*)d_in[4];
    const float* my      = (const float*)d_in[5];
    const int*   pscale  = (const int*)d_in[6];
    float* out = (float*)d_out;
    float* wsf = (float*)d_ws;   // 512 partial sums

    fused_kernel<<<BB, 256, 0, stream>>>(p, A, C, d, sigma_p, my, pscale, wsf);
    reduce_kernel<<<1, 512, 0, stream>>>(wsf, out);
}